// Round 4
// baseline (261.962 us; speedup 1.0000x reference)
//
#include <hip/hip_runtime.h>
#include <hip/hip_bf16.h>
#include <stdint.h>

// Problem dims: T=8192 tokens, H=2048 hidden, I=768 intermediate
// fp32 in/out; internal bf16 MFMA (absmax 0.0156 vs 0.074 budget).
#define T_DIM 8192
#define H_DIM 2048
#define I_DIM 768

typedef __bf16 bf16_t;
typedef bf16_t bf16x8 __attribute__((ext_vector_type(8)));
typedef bf16_t bf16x4 __attribute__((ext_vector_type(4)));
typedef float  f32x4  __attribute__((ext_vector_type(4)));

// Async global->LDS, 16B per lane. LDS dest must be wave-uniform base + lane*16
// (linear). Any swizzle goes on the GLOBAL source + the ds_read address.
__device__ __forceinline__ void async_load16(const void* g, void* s) {
    __builtin_amdgcn_global_load_lds(
        (const __attribute__((address_space(1))) void*)g,
        (__attribute__((address_space(3))) void*)s, 16, 0, 0);
}

// ---------------------------------------------------------------------------
// Kernel 0 (R3 version, byte-identical): fp32 -> bf16 of all four inputs.
// ---------------------------------------------------------------------------
__global__ __launch_bounds__(256) void cvt_kernel(
    const float* __restrict__ X, const float* __restrict__ G,
    const float* __restrict__ U, const float* __restrict__ D,
    bf16_t* __restrict__ Xb, bf16_t* __restrict__ Gb,
    bf16_t* __restrict__ Ub, bf16_t* __restrict__ Db)
{
    const size_t N8X = (size_t)T_DIM * H_DIM / 8;
    const size_t N8W = (size_t)I_DIM * H_DIM / 8;
    const size_t total = N8X + 3 * N8W;
    for (size_t i = (size_t)blockIdx.x * blockDim.x + threadIdx.x; i < total;
         i += (size_t)gridDim.x * blockDim.x) {
        const float* s; bf16_t* d; size_t j = i;
        if (j < N8X) { s = X; d = Xb; }
        else {
            j -= N8X;
            if (j < N8W) { s = G; d = Gb; }
            else { j -= N8W;
                if (j < N8W) { s = U; d = Ub; }
                else { j -= N8W; s = D; d = Db; } }
        }
        float4 v0 = ((const float4*)s)[2 * j];
        float4 v1 = ((const float4*)s)[2 * j + 1];
        bf16x8 o;
        o[0] = (bf16_t)v0.x; o[1] = (bf16_t)v0.y; o[2] = (bf16_t)v0.z; o[3] = (bf16_t)v0.w;
        o[4] = (bf16_t)v1.x; o[5] = (bf16_t)v1.y; o[6] = (bf16_t)v1.z; o[7] = (bf16_t)v1.w;
        ((bf16x8*)d)[j] = o;
    }
}

// ---------------------------------------------------------------------------
// Kernel 1 v4: SAME r0 schedule (single LDS buffer, BK=32, plain
// __syncthreads, 128x64 tile, grid 64x12 = 768 = 3 blocks/CU) -- schedule
// changes measured worse (R1 dbuf+vmcnt: 87us, R2 BK64: 80us).
// Changes vs r0 target the measured pipes only:
//  (a) 8 waves of 512 threads (2M x 4N, wave owns 64x16 of G and U):
//      24 waves/CU vs 12 -> latency hiding. acc halves to 32 VGPR;
//      __launch_bounds__(512,8) forces VGPR<=64 (occupancy quantum: waves
//      halve at 64/128; >64 would mean 2 blocks/CU = 1.5 rounds = loss).
//  (b) R1-proven involution swizzle (harness-verified): zero the measured
//      4 cyc/ds_read conflict tax. Rows = 64B = 4 slots; stored slot =
//      c ^ ((row>>1)&3); global source pre-swizzled, LDS dest linear.
// LDS-read budget/step/CU: 3 blk x 48 reads x 12 cyc = 1728 < 2400 current.
// ---------------------------------------------------------------------------
__global__ __launch_bounds__(512, 8) void gateup_kernel(
    const bf16_t* __restrict__ X,
    const bf16_t* __restrict__ Wg,
    const bf16_t* __restrict__ Wu,
    bf16_t* __restrict__ Hbuf)
{
    __shared__ __align__(16) bf16_t sA[128 * 32];   // x tile       8 KB
    __shared__ __align__(16) bf16_t sG[64 * 32];    // gate_w tile  4 KB
    __shared__ __align__(16) bf16_t sU[64 * 32];    // up_w tile    4 KB

    const int tid   = threadIdx.x;    // 0..511
    const int lane  = tid & 63;
    const int wave  = tid >> 6;       // 0..7
    const int waveM = wave >> 2;      // 0..1 -> 64-row half
    const int waveN = wave & 3;       // 0..3 -> 16-col quarter
    const int quad  = lane >> 4;      // 0..3
    const int lrow  = lane & 15;      // 0..15

    const int blockM = blockIdx.x;    // 0..63  (T/128)
    const int blockN = blockIdx.y;    // 0..11  (I/64)

    f32x4 accG[4], accU[4];
#pragma unroll
    for (int i = 0; i < 4; i++) { accG[i] = (f32x4)(0.f); accU[i] = (f32x4)(0.f); }

    // Staging: A 512 x 16B segs (1/thread); G 256 segs (waves 0-3, 1/thread);
    // U 256 segs (waves 4-7, 1/thread). LDS dest linear = seg*16B (wave-
    // uniform base + lane*16 ok: G/U split is at wave granularity).
    // Source col-block swizzled: c = (s&3) ^ ((row>>1)&3), elements c*8.
    const int sa = tid;
    const int rA = sa >> 2, cA = (((sa & 3) ^ ((rA >> 1) & 3)) * 8);
    const int sw = tid & 255;
    const int rW = sw >> 2, cW = (((sw & 3) ^ ((rW >> 1) & 3)) * 8);

    const bf16_t* Ab = X  + (size_t)(blockM * 128) * H_DIM;
    const bf16_t* Wb = ((tid < 256) ? Wg : Wu) + (size_t)(blockN * 64) * H_DIM;
    bf16_t* sW = (tid < 256) ? &sG[sw * 8] : &sU[sw * 8];

    // Read-side swizzled element offsets (loop-invariant).
    int aOff[4];
#pragma unroll
    for (int mi = 0; mi < 4; mi++) {
        int r = waveM * 64 + mi * 16 + lrow;
        aOff[mi] = r * 32 + ((quad ^ ((r >> 1) & 3)) * 8);
    }
    const int rw = waveN * 16 + lrow;
    const int wOff = rw * 32 + ((quad ^ ((rw >> 1) & 3)) * 8);

    for (int k0 = 0; k0 < H_DIM; k0 += 32) {
        async_load16(Ab + (size_t)rA * H_DIM + k0 + cA, &sA[sa * 8]);
        async_load16(Wb + (size_t)rW * H_DIM + k0 + cW, sW);
        __syncthreads();   // vmcnt(0) drain + barrier

        bf16x8 aF[4], gF, uF;
#pragma unroll
        for (int mi = 0; mi < 4; mi++)
            aF[mi] = *(const bf16x8*)&sA[aOff[mi]];
        gF = *(const bf16x8*)&sG[wOff];
        uF = *(const bf16x8*)&sU[wOff];
        __syncthreads();   // frags in regs; next iter overwrites LDS

#pragma unroll
        for (int mi = 0; mi < 4; mi++) {
            accG[mi] = __builtin_amdgcn_mfma_f32_16x16x32_bf16(aF[mi], gF, accG[mi], 0, 0, 0);
            accU[mi] = __builtin_amdgcn_mfma_f32_16x16x32_bf16(aF[mi], uF, accU[mi], 0, 0, 0);
        }
    }

    // Epilogue: h = silu(g)*u, cast bf16. C/D layout: col=lane&15, row=quad*4+r.
#pragma unroll
    for (int mi = 0; mi < 4; mi++) {
#pragma unroll
        for (int r = 0; r < 4; r++) {
            int row = blockM * 128 + waveM * 64 + mi * 16 + quad * 4 + r;
            int col = blockN * 64 + waveN * 16 + lrow;
            float g = accG[mi][r];
            float u = accU[mi][r];
            float h = (g / (1.f + __expf(-g))) * u;
            Hbuf[(size_t)row * I_DIM + col] = (bf16_t)h;
        }
    }
}

// ---------------------------------------------------------------------------
// Kernel 2 (R3 version, byte-identical): out[T,H] = h @ down^T. 128x128
// tiles, grid 64x16 = 1024 (4/CU), BK=64 (12 K-steps), XOR LDS swizzle.
// ---------------------------------------------------------------------------
__global__ __launch_bounds__(256, 4) void down_kernel(
    const bf16_t* __restrict__ Hbuf,
    const bf16_t* __restrict__ Wd,
    float* __restrict__ Out)
{
    __shared__ __align__(16) bf16_t sA[128 * 64];   // 16 KB
    __shared__ __align__(16) bf16_t sB[128 * 64];   // 16 KB

    const int tid   = threadIdx.x;
    const int lane  = tid & 63;
    const int wave  = tid >> 6;
    const int waveM = wave >> 1;
    const int waveN = wave & 1;
    const int quad  = lane >> 4;
    const int lrow  = lane & 15;

    const int blockM = blockIdx.x;    // 0..63  (T/128)
    const int blockN = blockIdx.y;    // 0..15  (H/128)

    f32x4 acc[4][4];
#pragma unroll
    for (int i = 0; i < 4; i++)
#pragma unroll
        for (int j = 0; j < 4; j++) acc[i][j] = (f32x4)(0.f);

    const bf16_t* Ab = Hbuf + (size_t)(blockM * 128) * I_DIM;
    const bf16_t* Bb = Wd   + (size_t)(blockN * 128) * I_DIM;

    int gRow[4], gCol[4];   // staging source per segment (shared by A and B)
#pragma unroll
    for (int i = 0; i < 4; i++) {
        int s = tid + 256 * i;
        gRow[i] = s >> 3;
        gCol[i] = ((s & 7) ^ ((s >> 3) & 7)) * 8;
    }

    int aOff[4], bOff[4];
#pragma unroll
    for (int mi = 0; mi < 4; mi++) {
        int r = waveM * 64 + mi * 16 + lrow;
        aOff[mi] = r * 64 + ((quad ^ (r & 7)) * 8);
    }
#pragma unroll
    for (int ni = 0; ni < 4; ni++) {
        int r = waveN * 64 + ni * 16 + lrow;
        bOff[ni] = r * 64 + ((quad ^ (r & 7)) * 8);
    }

    for (int k0 = 0; k0 < I_DIM; k0 += 64) {
#pragma unroll
        for (int i = 0; i < 4; i++) {
            async_load16(Ab + (size_t)gRow[i] * I_DIM + k0 + gCol[i],
                         &sA[(tid + 256 * i) * 8]);
            async_load16(Bb + (size_t)gRow[i] * I_DIM + k0 + gCol[i],
                         &sB[(tid + 256 * i) * 8]);
        }
        __syncthreads();

#pragma unroll
        for (int kk = 0; kk < 2; kk++) {
            const int kx = kk * 32;   // slot^4 <=> element offset ^32
            bf16x8 aF[4], bF[4];
#pragma unroll
            for (int mi = 0; mi < 4; mi++)
                aF[mi] = *(const bf16x8*)&sA[aOff[mi] ^ kx];
#pragma unroll
            for (int ni = 0; ni < 4; ni++)
                bF[ni] = *(const bf16x8*)&sB[bOff[ni] ^ kx];
#pragma unroll
            for (int mi = 0; mi < 4; mi++)
#pragma unroll
                for (int ni = 0; ni < 4; ni++)
                    acc[mi][ni] = __builtin_amdgcn_mfma_f32_16x16x32_bf16(aF[mi], bF[ni], acc[mi][ni], 0, 0, 0);
        }
        __syncthreads();
    }

#pragma unroll
    for (int mi = 0; mi < 4; mi++) {
#pragma unroll
        for (int ni = 0; ni < 4; ni++) {
#pragma unroll
            for (int r = 0; r < 4; r++) {
                int row = blockM * 128 + waveM * 64 + mi * 16 + quad * 4 + r;
                int col = blockN * 128 + waveN * 64 + ni * 16 + lrow;
                Out[(size_t)row * H_DIM + col] = acc[mi][ni][r];
            }
        }
    }
}

extern "C" void kernel_launch(void* const* d_in, const int* in_sizes, int n_in,
                              void* d_out, int out_size, void* d_ws, size_t ws_size,
                              hipStream_t stream) {
    const float* x  = (const float*)d_in[0];  // [T, H] fp32
    const float* gw = (const float*)d_in[1];  // [I, H] fp32
    const float* uw = (const float*)d_in[2];  // [I, H] fp32
    const float* dw = (const float*)d_in[3];  // [H, I] fp32
    float* out = (float*)d_out;               // [T, H] fp32

    bf16_t* xb = (bf16_t*)d_ws;
    bf16_t* gb = xb + (size_t)T_DIM * H_DIM;
    bf16_t* ub = gb + (size_t)I_DIM * H_DIM;
    bf16_t* db = ub + (size_t)I_DIM * H_DIM;
    bf16_t* hb = db + (size_t)I_DIM * H_DIM;

    cvt_kernel<<<2048, 256, 0, stream>>>(x, gw, uw, dw, xb, gb, ub, db);
    gateup_kernel<<<dim3(T_DIM / 128, I_DIM / 64), 512, 0, stream>>>(xb, gb, ub, hb);
    down_kernel<<<dim3(T_DIM / 128, H_DIM / 128), 256, 0, stream>>>(hb, db, out);
}

// Round 5
// 236.437 us; speedup vs baseline: 1.1080x; 1.1080x over previous
//
#include <hip/hip_runtime.h>
#include <hip/hip_bf16.h>
#include <stdint.h>

// Problem dims: T=8192 tokens, H=2048 hidden, I=768 intermediate
// fp32 in/out; internal bf16 MFMA (absmax 0.0156 vs 0.074 budget).
#define T_DIM 8192
#define H_DIM 2048
#define I_DIM 768

typedef __bf16 bf16_t;
typedef bf16_t bf16x8 __attribute__((ext_vector_type(8)));
typedef bf16_t bf16x4 __attribute__((ext_vector_type(4)));
typedef float  f32x4  __attribute__((ext_vector_type(4)));

// Async global->LDS, 16B per lane (used by down_kernel only; LDS dest must be
// wave-uniform base + lane*16, linear).
__device__ __forceinline__ void async_load16(const void* g, void* s) {
    __builtin_amdgcn_global_load_lds(
        (const __attribute__((address_space(1))) void*)g,
        (__attribute__((address_space(3))) void*)s, 16, 0, 0);
}

__device__ __forceinline__ bf16x8 cvt8(float4 a, float4 b) {
    bf16x8 o;
    o[0] = (bf16_t)a.x; o[1] = (bf16_t)a.y; o[2] = (bf16_t)a.z; o[3] = (bf16_t)a.w;
    o[4] = (bf16_t)b.x; o[5] = (bf16_t)b.y; o[6] = (bf16_t)b.z; o[7] = (bf16_t)b.w;
    return o;
}

// ---------------------------------------------------------------------------
// Kernel 0: fp32 -> bf16 for down_w ONLY (~12.6 MB traffic, ~3 us).
// X / gate_w / up_w are now converted inline inside gateup_kernel.
// ---------------------------------------------------------------------------
__global__ __launch_bounds__(256) void cvt_d_kernel(
    const float* __restrict__ D, bf16_t* __restrict__ Db)
{
    const size_t N8 = (size_t)I_DIM * H_DIM / 8;   // 196,608
    for (size_t j = (size_t)blockIdx.x * blockDim.x + threadIdx.x; j < N8;
         j += (size_t)gridDim.x * blockDim.x) {
        float4 v0 = ((const float4*)D)[2 * j];
        float4 v1 = ((const float4*)D)[2 * j + 1];
        ((bf16x8*)Db)[j] = cvt8(v0, v1);
    }
}

// ---------------------------------------------------------------------------
// Kernel 1 v5: r0 schedule (single LDS buffer, BK=32, two plain barriers,
// 128x64 tile, 4 waves 2x2, grid 64x12 = 3 blocks/CU -- every schedule
// perturbation measured worse: R1 dbuf+vmcnt 87us, R2 BK64 80us, R4
// 8-wave+launch_bounds spilled to scratch, 102us).  Changes vs r0:
//  (a) Reads fp32 X/Wg/Wu DIRECTLY: float4 pair -> cvt -> ds_write_b128.
//      Eliminates the ~130 MB cvt pass for these arrays. Loads are issued
//      before the first barrier so their latency hides under the previous
//      iteration's MFMA + barrier wait (T14-lite). No gload_lds for these.
//  (b) Reg-staging frees the LDS dest -> write-side XOR swizzle (stored
//      slot = c ^ ((row>>1)&3); same mapping harness-verified in R1) zeroes
//      the measured 4 cyc/ds_read conflict tax. ds_writes stay conflict-free
//      (slot permutation within a row).
// ---------------------------------------------------------------------------
__global__ __launch_bounds__(256) void gateup_kernel(
    const float* __restrict__ Xf,
    const float* __restrict__ Wgf,
    const float* __restrict__ Wuf,
    bf16_t* __restrict__ Hbuf)
{
    __shared__ __align__(16) bf16_t sA[128 * 32];   // x tile       8 KB
    __shared__ __align__(16) bf16_t sG[64 * 32];    // gate_w tile  4 KB
    __shared__ __align__(16) bf16_t sU[64 * 32];    // up_w tile    4 KB

    const int tid   = threadIdx.x;
    const int lane  = tid & 63;
    const int wave  = tid >> 6;
    const int waveM = wave >> 1;      // 0..1 -> 64-row half
    const int waveN = wave & 1;       // 0..1 -> 32-col half
    const int quad  = lane >> 4;      // 0..3
    const int lrow  = lane & 15;      // 0..15

    const int blockM = blockIdx.x;    // 0..63  (T/128)
    const int blockN = blockIdx.y;    // 0..11  (I/64)

    f32x4 accG[4][2], accU[4][2];
#pragma unroll
    for (int i = 0; i < 4; i++)
#pragma unroll
        for (int j = 0; j < 2; j++) { accG[i][j] = (f32x4)(0.f); accU[i][j] = (f32x4)(0.f); }

    // Staging map (r0): A 512 x 16B segs (2/thread: s0=tid, s1=tid+256);
    // G/U 256 segs (1/thread each). Seg s: row = s>>2, natural col-slot s&3.
    // Global source col stays NATURAL; LDS dest slot is swizzled.
    const int s0 = tid, s1 = tid + 256;
    const int rA0 = s0 >> 2, cA0 = (s0 & 3) * 8;
    const int rA1 = s1 >> 2, cA1 = (s1 & 3) * 8;
    const int rW  = tid >> 2, cW  = (tid & 3) * 8;

    // Swizzled LDS element offsets for the staged 16B segments.
    const int dA0 = rA0 * 32 + (((s0 & 3) ^ ((rA0 >> 1) & 3)) * 8);
    const int dA1 = rA1 * 32 + (((s1 & 3) ^ ((rA1 >> 1) & 3)) * 8);
    const int dW  = rW  * 32 + (((tid & 3) ^ ((rW  >> 1) & 3)) * 8);

    const float* Ab0 = Xf  + (size_t)(blockM * 128 + rA0) * H_DIM + cA0;
    const float* Ab1 = Xf  + (size_t)(blockM * 128 + rA1) * H_DIM + cA1;
    const float* Gb  = Wgf + (size_t)(blockN * 64  + rW ) * H_DIM + cW;
    const float* Ub  = Wuf + (size_t)(blockN * 64  + rW ) * H_DIM + cW;

    // Read-side swizzled frag offsets (same formula as write side).
    int aOff[4], wOff[2];
#pragma unroll
    for (int mi = 0; mi < 4; mi++) {
        int r = waveM * 64 + mi * 16 + lrow;
        aOff[mi] = r * 32 + ((quad ^ ((r >> 1) & 3)) * 8);
    }
#pragma unroll
    for (int ni = 0; ni < 2; ni++) {
        int r = waveN * 32 + ni * 16 + lrow;
        wOff[ni] = r * 32 + ((quad ^ ((r >> 1) & 3)) * 8);
    }

    for (int k0 = 0; k0 < H_DIM; k0 += 32) {
        // Issue all global loads FIRST (registers; no LDS touched yet).
        float4 a00 = ((const float4*)(Ab0 + k0))[0];
        float4 a01 = ((const float4*)(Ab0 + k0))[1];
        float4 a10 = ((const float4*)(Ab1 + k0))[0];
        float4 a11 = ((const float4*)(Ab1 + k0))[1];
        float4 g0  = ((const float4*)(Gb  + k0))[0];
        float4 g1  = ((const float4*)(Gb  + k0))[1];
        float4 u0  = ((const float4*)(Ub  + k0))[0];
        float4 u1  = ((const float4*)(Ub  + k0))[1];

        __syncthreads();   // all waves done reading prev iter's frags

        *(bf16x8*)&sA[dA0] = cvt8(a00, a01);
        *(bf16x8*)&sA[dA1] = cvt8(a10, a11);
        *(bf16x8*)&sG[dW]  = cvt8(g0, g1);
        *(bf16x8*)&sU[dW]  = cvt8(u0, u1);

        __syncthreads();   // staging complete

        bf16x8 aF[4], gF[2], uF[2];
#pragma unroll
        for (int mi = 0; mi < 4; mi++)
            aF[mi] = *(const bf16x8*)&sA[aOff[mi]];
#pragma unroll
        for (int ni = 0; ni < 2; ni++) {
            gF[ni] = *(const bf16x8*)&sG[wOff[ni]];
            uF[ni] = *(const bf16x8*)&sU[wOff[ni]];
        }

#pragma unroll
        for (int mi = 0; mi < 4; mi++)
#pragma unroll
            for (int ni = 0; ni < 2; ni++) {
                accG[mi][ni] = __builtin_amdgcn_mfma_f32_16x16x32_bf16(aF[mi], gF[ni], accG[mi][ni], 0, 0, 0);
                accU[mi][ni] = __builtin_amdgcn_mfma_f32_16x16x32_bf16(aF[mi], uF[ni], accU[mi][ni], 0, 0, 0);
            }
    }

    // Epilogue: h = silu(g)*u, cast bf16. C/D layout: col=lane&15, row=quad*4+r.
#pragma unroll
    for (int mi = 0; mi < 4; mi++) {
#pragma unroll
        for (int ni = 0; ni < 2; ni++) {
#pragma unroll
            for (int r = 0; r < 4; r++) {
                int row = blockM * 128 + waveM * 64 + mi * 16 + quad * 4 + r;
                int col = blockN * 64 + waveN * 32 + ni * 16 + lrow;
                float g = accG[mi][ni][r];
                float u = accU[mi][ni][r];
                float h = (g / (1.f + __expf(-g))) * u;
                Hbuf[(size_t)row * I_DIM + col] = (bf16_t)h;
            }
        }
    }
}

// ---------------------------------------------------------------------------
// Kernel 2 (R3 version, byte-identical): out[T,H] = h @ down^T. 128x128
// tiles, grid 64x16 = 1024 (4/CU), BK=64 (12 K-steps), XOR LDS swizzle.
// ---------------------------------------------------------------------------
__global__ __launch_bounds__(256, 4) void down_kernel(
    const bf16_t* __restrict__ Hbuf,
    const bf16_t* __restrict__ Wd,
    float* __restrict__ Out)
{
    __shared__ __align__(16) bf16_t sA[128 * 64];   // 16 KB
    __shared__ __align__(16) bf16_t sB[128 * 64];   // 16 KB

    const int tid   = threadIdx.x;
    const int lane  = tid & 63;
    const int wave  = tid >> 6;
    const int waveM = wave >> 1;
    const int waveN = wave & 1;
    const int quad  = lane >> 4;
    const int lrow  = lane & 15;

    const int blockM = blockIdx.x;    // 0..63  (T/128)
    const int blockN = blockIdx.y;    // 0..15  (H/128)

    f32x4 acc[4][4];
#pragma unroll
    for (int i = 0; i < 4; i++)
#pragma unroll
        for (int j = 0; j < 4; j++) acc[i][j] = (f32x4)(0.f);

    const bf16_t* Ab = Hbuf + (size_t)(blockM * 128) * I_DIM;
    const bf16_t* Bb = Wd   + (size_t)(blockN * 128) * I_DIM;

    int gRow[4], gCol[4];   // staging source per segment (shared by A and B)
#pragma unroll
    for (int i = 0; i < 4; i++) {
        int s = tid + 256 * i;
        gRow[i] = s >> 3;
        gCol[i] = ((s & 7) ^ ((s >> 3) & 7)) * 8;
    }

    int aOff[4], bOff[4];
#pragma unroll
    for (int mi = 0; mi < 4; mi++) {
        int r = waveM * 64 + mi * 16 + lrow;
        aOff[mi] = r * 64 + ((quad ^ (r & 7)) * 8);
    }
#pragma unroll
    for (int ni = 0; ni < 4; ni++) {
        int r = waveN * 64 + ni * 16 + lrow;
        bOff[ni] = r * 64 + ((quad ^ (r & 7)) * 8);
    }

    for (int k0 = 0; k0 < I_DIM; k0 += 64) {
#pragma unroll
        for (int i = 0; i < 4; i++) {
            async_load16(Ab + (size_t)gRow[i] * I_DIM + k0 + gCol[i],
                         &sA[(tid + 256 * i) * 8]);
            async_load16(Bb + (size_t)gRow[i] * I_DIM + k0 + gCol[i],
                         &sB[(tid + 256 * i) * 8]);
        }
        __syncthreads();

#pragma unroll
        for (int kk = 0; kk < 2; kk++) {
            const int kx = kk * 32;   // slot^4 <=> element offset ^32
            bf16x8 aF[4], bF[4];
#pragma unroll
            for (int mi = 0; mi < 4; mi++)
                aF[mi] = *(const bf16x8*)&sA[aOff[mi] ^ kx];
#pragma unroll
            for (int ni = 0; ni < 4; ni++)
                bF[ni] = *(const bf16x8*)&sB[bOff[ni] ^ kx];
#pragma unroll
            for (int mi = 0; mi < 4; mi++)
#pragma unroll
                for (int ni = 0; ni < 4; ni++)
                    acc[mi][ni] = __builtin_amdgcn_mfma_f32_16x16x32_bf16(aF[mi], bF[ni], acc[mi][ni], 0, 0, 0);
        }
        __syncthreads();
    }

#pragma unroll
    for (int mi = 0; mi < 4; mi++) {
#pragma unroll
        for (int ni = 0; ni < 4; ni++) {
#pragma unroll
            for (int r = 0; r < 4; r++) {
                int row = blockM * 128 + waveM * 64 + mi * 16 + quad * 4 + r;
                int col = blockN * 128 + waveN * 64 + ni * 16 + lrow;
                Out[(size_t)row * H_DIM + col] = acc[mi][ni][r];
            }
        }
    }
}

extern "C" void kernel_launch(void* const* d_in, const int* in_sizes, int n_in,
                              void* d_out, int out_size, void* d_ws, size_t ws_size,
                              hipStream_t stream) {
    const float* x  = (const float*)d_in[0];  // [T, H] fp32
    const float* gw = (const float*)d_in[1];  // [I, H] fp32
    const float* uw = (const float*)d_in[2];  // [I, H] fp32
    const float* dw = (const float*)d_in[3];  // [H, I] fp32
    float* out = (float*)d_out;               // [T, H] fp32

    // Workspace (bf16): dw_bf [I*H], hbuf [T*I].
    bf16_t* db = (bf16_t*)d_ws;
    bf16_t* hb = db + (size_t)I_DIM * H_DIM;

    cvt_d_kernel<<<512, 256, 0, stream>>>(dw, db);
    gateup_kernel<<<dim3(T_DIM / 128, I_DIM / 64), 256, 0, stream>>>(x, gw, uw, hb);
    down_kernel<<<dim3(T_DIM / 128, H_DIM / 128), 256, 0, stream>>>(hb, db, out);
}

// Round 6
// 221.548 us; speedup vs baseline: 1.1824x; 1.0672x over previous
//
#include <hip/hip_runtime.h>
#include <hip/hip_bf16.h>
#include <stdint.h>

// Problem dims: T=8192 tokens, H=2048 hidden, I=768 intermediate
// fp32 in/out; internal bf16 MFMA (absmax 0.0156 vs 0.074 budget).
#define T_DIM 8192
#define H_DIM 2048
#define I_DIM 768

typedef __bf16 bf16_t;
typedef bf16_t bf16x8 __attribute__((ext_vector_type(8)));
typedef bf16_t bf16x4 __attribute__((ext_vector_type(4)));
typedef float  f32x4  __attribute__((ext_vector_type(4)));

// Async global->LDS, 16B per lane. LDS dest must be wave-uniform base + lane*16
// (linear). Any swizzle goes on the GLOBAL source + the ds_read address.
__device__ __forceinline__ void async_load16(const void* g, void* s) {
    __builtin_amdgcn_global_load_lds(
        (const __attribute__((address_space(1))) void*)g,
        (__attribute__((address_space(3))) void*)s, 16, 0, 0);
}

// Raw barrier with compiler memory fences on both sides: prevents the
// scheduler from hoisting gload_lds/ds ops across the barrier (raw
// s_barrier has NO implicit fence; race-safety of the phase schedule
// depends on memory ops staying inside their phase).
__device__ __forceinline__ void phase_barrier() {
    asm volatile("" ::: "memory");
    __builtin_amdgcn_s_barrier();
    asm volatile("" ::: "memory");
}

__device__ __forceinline__ bf16x8 cvt8(float4 a, float4 b) {
    bf16x8 o;
    o[0] = (bf16_t)a.x; o[1] = (bf16_t)a.y; o[2] = (bf16_t)a.z; o[3] = (bf16_t)a.w;
    o[4] = (bf16_t)b.x; o[5] = (bf16_t)b.y; o[6] = (bf16_t)b.z; o[7] = (bf16_t)b.w;
    return o;
}

// ---------------------------------------------------------------------------
// Kernel 0 (R3 version, byte-identical): fp32 -> bf16 of all four inputs.
// ---------------------------------------------------------------------------
__global__ __launch_bounds__(256) void cvt_kernel(
    const float* __restrict__ X, const float* __restrict__ G,
    const float* __restrict__ U, const float* __restrict__ D,
    bf16_t* __restrict__ Xb, bf16_t* __restrict__ Gb,
    bf16_t* __restrict__ Ub, bf16_t* __restrict__ Db)
{
    const size_t N8X = (size_t)T_DIM * H_DIM / 8;
    const size_t N8W = (size_t)I_DIM * H_DIM / 8;
    const size_t total = N8X + 3 * N8W;
    for (size_t i = (size_t)blockIdx.x * blockDim.x + threadIdx.x; i < total;
         i += (size_t)gridDim.x * blockDim.x) {
        const float* s; bf16_t* d; size_t j = i;
        if (j < N8X) { s = X; d = Xb; }
        else {
            j -= N8X;
            if (j < N8W) { s = G; d = Gb; }
            else { j -= N8W;
                if (j < N8W) { s = U; d = Ub; }
                else { j -= N8W; s = D; d = Db; } }
        }
        float4 v0 = ((const float4*)s)[2 * j];
        float4 v1 = ((const float4*)s)[2 * j + 1];
        ((bf16x8*)d)[j] = cvt8(v0, v1);
    }
}

// ---------------------------------------------------------------------------
// Kernel 1 (r0 form, proven 64 us -- 4 perturbations all measured worse;
// do not touch): 128x64 tile, 4 waves 2x2, BK=32, single LDS buffer,
// plain __syncthreads, grid 64x12 = 3 blocks/CU.
// ---------------------------------------------------------------------------
__global__ __launch_bounds__(256) void gateup_kernel(
    const bf16_t* __restrict__ X,
    const bf16_t* __restrict__ Wg,
    const bf16_t* __restrict__ Wu,
    bf16_t* __restrict__ Hbuf)
{
    __shared__ __align__(16) bf16_t sA[128 * 32];   // x tile       8 KB
    __shared__ __align__(16) bf16_t sG[64 * 32];    // gate_w tile  4 KB
    __shared__ __align__(16) bf16_t sU[64 * 32];    // up_w tile    4 KB

    const int tid   = threadIdx.x;
    const int lane  = tid & 63;
    const int wave  = tid >> 6;
    const int waveM = wave >> 1;
    const int waveN = wave & 1;
    const int quad  = lane >> 4;
    const int lrow  = lane & 15;

    const int blockM = blockIdx.x;    // 0..63  (T/128)
    const int blockN = blockIdx.y;    // 0..11  (I/64)

    f32x4 accG[4][2], accU[4][2];
#pragma unroll
    for (int i = 0; i < 4; i++)
#pragma unroll
        for (int j = 0; j < 2; j++) { accG[i][j] = (f32x4)(0.f); accU[i][j] = (f32x4)(0.f); }

    const int s0 = tid, s1 = tid + 256;
    const int rA0 = s0 >> 2, cA0 = (s0 & 3) * 8;
    const int rA1 = s1 >> 2, cA1 = (s1 & 3) * 8;
    const int rW  = tid >> 2, cW  = (tid & 3) * 8;

    const bf16_t* Ab = X  + (size_t)(blockM * 128) * H_DIM;
    const bf16_t* Gb = Wg + (size_t)(blockN * 64) * H_DIM;
    const bf16_t* Ub = Wu + (size_t)(blockN * 64) * H_DIM;

    for (int k0 = 0; k0 < H_DIM; k0 += 32) {
        async_load16(Ab + (size_t)rA0 * H_DIM + k0 + cA0, &sA[s0 * 8]);
        async_load16(Ab + (size_t)rA1 * H_DIM + k0 + cA1, &sA[s1 * 8]);
        async_load16(Gb + (size_t)rW  * H_DIM + k0 + cW,  &sG[tid * 8]);
        async_load16(Ub + (size_t)rW  * H_DIM + k0 + cW,  &sU[tid * 8]);
        __syncthreads();   // vmcnt(0) drain + barrier

        bf16x8 aF[4], gF[2], uF[2];
#pragma unroll
        for (int mi = 0; mi < 4; mi++) {
            int r = waveM * 64 + mi * 16 + lrow;
            aF[mi] = *(const bf16x8*)&sA[r * 32 + quad * 8];
        }
#pragma unroll
        for (int ni = 0; ni < 2; ni++) {
            int r = waveN * 32 + ni * 16 + lrow;
            gF[ni] = *(const bf16x8*)&sG[r * 32 + quad * 8];
            uF[ni] = *(const bf16x8*)&sU[r * 32 + quad * 8];
        }
        __syncthreads();   // frags in regs; next iter overwrites LDS

#pragma unroll
        for (int mi = 0; mi < 4; mi++)
#pragma unroll
            for (int ni = 0; ni < 2; ni++) {
                accG[mi][ni] = __builtin_amdgcn_mfma_f32_16x16x32_bf16(aF[mi], gF[ni], accG[mi][ni], 0, 0, 0);
                accU[mi][ni] = __builtin_amdgcn_mfma_f32_16x16x32_bf16(aF[mi], uF[ni], accU[mi][ni], 0, 0, 0);
            }
    }

#pragma unroll
    for (int mi = 0; mi < 4; mi++) {
#pragma unroll
        for (int ni = 0; ni < 2; ni++) {
#pragma unroll
            for (int r = 0; r < 4; r++) {
                int row = blockM * 128 + waveM * 64 + mi * 16 + quad * 4 + r;
                int col = blockN * 64 + waveN * 32 + ni * 16 + lrow;
                float g = accG[mi][ni][r];
                float u = accU[mi][ni][r];
                float h = (g / (1.f + __expf(-g))) * u;
                Hbuf[(size_t)row * I_DIM + col] = (bf16_t)h;
            }
        }
    }
}

// ---------------------------------------------------------------------------
// Kernel 2 v6: 256x256 8-phase deep-pipelined GEMM (m201 template, plain
// HIP).  out[T,H] = h @ down^T, K = 768 = 12 K-tiles of BK=64.
// Grid 32x8 = 256 blocks = 1/CU; 512 threads = 8 waves (2M x 4N); each wave
// owns a 128x64 output tile (acc[8][4] f32x4 = 128 VGPR).
// LDS 128 KB: sA[2][256*64] + sB[2][256*64] bf16 (double-buffered K-tiles).
// Schedule per K-tile t (buf p = t&1): 4 phases, phase q computes M-quadrant
// mi in {2q, 2q+1}:
//   q0: ds_read B-full(8) + A-quad(4); stage A(t+1)->sA[p^1]; bar;
//       lgkmcnt(0); setprio1; 16 MFMA; setprio0; bar
//   q1: ds_read A-quad(4); stage B(t+2)->sB[p]  (B[p] fully consumed in q0,
//       guarded by q0's closing barrier); bar; ... MFMA ...; bar
//   q2, q3: ds_read A-quad(4); ... MFMA ...
//   end:  s_waitcnt vmcnt(4)  -- tile t+1's 8 loads done, B(t+2)'s 4 still
//         in flight (counted, never 0 mid-loop) -- then barrier.
// Swizzle: rows are 64 bf16 = 8 x 16B slots; stored slot = c ^ (row&7)
// (R2-harness-verified involution); linear gload_lds dest + pre-swizzled
// global source + XOR'd ds_read address.
// ---------------------------------------------------------------------------
__global__ __launch_bounds__(512, 2) void down_kernel(
    const bf16_t* __restrict__ Hbuf,
    const bf16_t* __restrict__ Wd,
    float* __restrict__ Out)
{
    __shared__ __align__(16) bf16_t sA[2][256 * 64];   // 2 x 32 KB
    __shared__ __align__(16) bf16_t sB[2][256 * 64];   // 2 x 32 KB

    const int tid  = threadIdx.x;     // 0..511
    const int lane = tid & 63;
    const int wave = tid >> 6;        // 0..7
    const int wm   = wave >> 2;       // 0..1 -> 128-row half
    const int wn   = wave & 3;        // 0..3 -> 64-col quarter
    const int quad = lane >> 4;       // 0..3
    const int lrow = lane & 15;       // 0..15

    const int bm = blockIdx.x;        // 0..31 (T/256)
    const int bn = blockIdx.y;        // 0..7  (H/256)

    f32x4 acc[8][4];
#pragma unroll
    for (int i = 0; i < 8; i++)
#pragma unroll
        for (int j = 0; j < 4; j++) acc[i][j] = (f32x4)(0.f);

    // Staging: one K-tile of A (or B) = 256 rows x 64 cols x 2B = 2048 x 16B
    // segs = 4 loads/thread. Seg s: row = s>>3, stored slot = s&7; source
    // col-block c = (s&7) ^ ((s>>3)&7)  (elements: c*8).
    int stRow[4], stCol[4];
#pragma unroll
    for (int i = 0; i < 4; i++) {
        int s = tid + 512 * i;
        stRow[i] = s >> 3;
        stCol[i] = ((s & 7) ^ ((s >> 3) & 7)) * 8;
    }

    const bf16_t* Ab = Hbuf + (size_t)(bm * 256) * I_DIM;
    const bf16_t* Bb = Wd   + (size_t)(bn * 256) * I_DIM;

#define STAGE_A(t) do { _Pragma("unroll") \
    for (int i_ = 0; i_ < 4; i_++) \
        async_load16(Ab + (size_t)stRow[i_] * I_DIM + (t) * 64 + stCol[i_], \
                     &sA[(t) & 1][(tid + 512 * i_) * 8]); } while (0)
#define STAGE_B(t) do { _Pragma("unroll") \
    for (int i_ = 0; i_ < 4; i_++) \
        async_load16(Bb + (size_t)stRow[i_] * I_DIM + (t) * 64 + stCol[i_], \
                     &sB[(t) & 1][(tid + 512 * i_) * 8]); } while (0)

    // Read-side swizzled element offsets, kk=0 (kk=1: XOR 32 <=> slot^4).
    int aOff[8], bOff[4];
#pragma unroll
    for (int mi = 0; mi < 8; mi++) {
        int r = wm * 128 + mi * 16 + lrow;
        aOff[mi] = r * 64 + ((quad ^ (r & 7)) * 8);
    }
#pragma unroll
    for (int ni = 0; ni < 4; ni++) {
        int r = wn * 64 + ni * 16 + lrow;
        bOff[ni] = r * 64 + ((quad ^ (r & 7)) * 8);
    }

    const int nt = I_DIM / 64;   // 12

    // Prologue: A(0), B(0), B(1) = 12 loads; wait the 8 oldest (tile 0).
    STAGE_A(0); STAGE_B(0); STAGE_B(1);
    asm volatile("s_waitcnt vmcnt(4)" ::: "memory");
    phase_barrier();

    for (int t = 0; t < nt; ++t) {
        const int p = t & 1;
        bf16x8 bF[4][2];   // lives across all 4 phases of this K-tile

#pragma unroll
        for (int q = 0; q < 4; ++q) {
            // --- ds-reads for this phase ---
            bf16x8 aF[2][2];
            if (q == 0) {
#pragma unroll
                for (int ni = 0; ni < 4; ni++) {
                    bF[ni][0] = *(const bf16x8*)&sB[p][bOff[ni]];
                    bF[ni][1] = *(const bf16x8*)&sB[p][bOff[ni] ^ 32];
                }
            }
#pragma unroll
            for (int j = 0; j < 2; j++) {
                aF[j][0] = *(const bf16x8*)&sA[p][aOff[2 * q + j]];
                aF[j][1] = *(const bf16x8*)&sA[p][aOff[2 * q + j] ^ 32];
            }
            // --- staggered prefetch (counted; regions consumed last phase) ---
            if (q == 0 && t + 1 < nt) STAGE_A(t + 1);   // -> sA[p^1]
            if (q == 1 && t + 2 < nt) STAGE_B(t + 2);   // -> sB[p]

            phase_barrier();
            asm volatile("s_waitcnt lgkmcnt(0)" ::: "memory");
            __builtin_amdgcn_sched_barrier(0);
            __builtin_amdgcn_s_setprio(1);
#pragma unroll
            for (int j = 0; j < 2; j++)
#pragma unroll
                for (int ni = 0; ni < 4; ni++)
#pragma unroll
                    for (int kk = 0; kk < 2; kk++)
                        acc[2 * q + j][ni] = __builtin_amdgcn_mfma_f32_16x16x32_bf16(
                            aF[j][kk], bF[ni][kk], acc[2 * q + j][ni], 0, 0, 0);
            __builtin_amdgcn_s_setprio(0);
            if (q < 3) phase_barrier();   // q3's closer is the vmcnt+barrier below
        }

        if (t < nt - 2) {
            // tile t+1 fully landed (A(t+1)@q0 + B(t+1) earlier); B(t+2)'s 4
            // loads stay in flight across the barrier.
            asm volatile("s_waitcnt vmcnt(4)" ::: "memory");
            phase_barrier();
        } else if (t == nt - 2) {
            asm volatile("s_waitcnt vmcnt(0)" ::: "memory");
            phase_barrier();
        }
        // t == nt-1: fall through to epilogue (nothing outstanding).
    }
#undef STAGE_A
#undef STAGE_B

    // Epilogue: C/D layout col=lane&15, row=quad*4+r.
#pragma unroll
    for (int mi = 0; mi < 8; mi++) {
#pragma unroll
        for (int ni = 0; ni < 4; ni++) {
#pragma unroll
            for (int r = 0; r < 4; r++) {
                int row = bm * 256 + wm * 128 + mi * 16 + quad * 4 + r;
                int col = bn * 256 + wn * 64 + ni * 16 + lrow;
                Out[(size_t)row * H_DIM + col] = acc[mi][ni][r];
            }
        }
    }
}

extern "C" void kernel_launch(void* const* d_in, const int* in_sizes, int n_in,
                              void* d_out, int out_size, void* d_ws, size_t ws_size,
                              hipStream_t stream) {
    const float* x  = (const float*)d_in[0];  // [T, H] fp32
    const float* gw = (const float*)d_in[1];  // [I, H] fp32
    const float* uw = (const float*)d_in[2];  // [I, H] fp32
    const float* dw = (const float*)d_in[3];  // [H, I] fp32
    float* out = (float*)d_out;               // [T, H] fp32

    // Workspace (bf16): x_bf [T*H], gw_bf/uw_bf/dw_bf [I*H], hbuf [T*I].
    bf16_t* xb = (bf16_t*)d_ws;
    bf16_t* gb = xb + (size_t)T_DIM * H_DIM;
    bf16_t* ub = gb + (size_t)I_DIM * H_DIM;
    bf16_t* db = ub + (size_t)I_DIM * H_DIM;
    bf16_t* hb = db + (size_t)I_DIM * H_DIM;

    cvt_kernel<<<2048, 256, 0, stream>>>(x, gw, uw, dw, xb, gb, ub, db);
    gateup_kernel<<<dim3(T_DIM / 128, I_DIM / 64), 256, 0, stream>>>(xb, gb, ub, hb);
    down_kernel<<<dim3(T_DIM / 256, H_DIM / 256), 512, 0, stream>>>(hb, db, out);
}